// Round 13
// baseline (39.718 us; speedup 1.0000x reference)
//
#include <hip/hip_runtime.h>
#include <hip/hip_bf16.h>

// DLRM forward, MI355X — round 13: r12 + micro-opt bundle:
//  (1) prep vectorized: 1 f16x8 fragment per thread (8 elems), grid 256x256
//  (2) lS_i preloaded to LDS in phase 0 (kills dependent-load chain in ph4)
//  (3) phase-4 gather batch-issued: all 16 float4 (2 rows) in flight at once
// Structure otherwise identical to r12 (32-row blocks, 1024 thr, 16 waves,
// fragment-tiled weights, XOR-swizzled LDS activations).

typedef _Float16 f16x8 __attribute__((ext_vector_type(8)));
typedef float f32x4 __attribute__((ext_vector_type(4)));

__device__ __forceinline__ f16x8 cvt8(float4 a, float4 b) {
  f16x8 f;
  f[0] = (_Float16)a.x; f[1] = (_Float16)a.y;
  f[2] = (_Float16)a.z; f[3] = (_Float16)a.w;
  f[4] = (_Float16)b.x; f[5] = (_Float16)b.y;
  f[6] = (_Float16)b.z; f[7] = (_Float16)b.w;
  return f;
}

// ---------------------------------------------------------------------------
// prep: weights -> f16 fragment-tiled images; 1 fragment (8 elems) / thread.
// Fragment layout: elem (c,k) of [M][Kpad] -> ((j*NKK+kk)*64 + lane)*8 + e.
// Fragment counts: w0 2048 | w1 16384 | w2 2048 | t0 28672 | t1 16384
//   total 65536 = 256 blocks * 256 threads.
// ---------------------------------------------------------------------------
__device__ __forceinline__ void frag_store(
    _Float16* __restrict__ dst, const float* __restrict__ src,
    int fl, int Ksrc, int NKK)
{
  int lane = fl & 63, q = fl >> 6;
  int kk = q % NKK, j = q / NKK;
  int c = j * 16 + (lane & 15);
  int kb = kk * 32 + (lane >> 4) * 8;
  const float* s = src + (size_t)c * Ksrc + kb;
  f16x8 o;
#pragma unroll
  for (int e = 0; e < 8; ++e)
    o[e] = (_Float16)((kb + e < Ksrc) ? s[e] : 0.0f);
  *(f16x8*)&dst[(size_t)fl * 8] = o;
}

__global__ __launch_bounds__(256) void prep_kernel(
    const float* __restrict__ bW0, const float* __restrict__ bW1,
    const float* __restrict__ bW2, const float* __restrict__ tW0,
    const float* __restrict__ tW1,
    _Float16* __restrict__ w0, _Float16* __restrict__ w1,
    _Float16* __restrict__ w2, _Float16* __restrict__ t0,
    _Float16* __restrict__ t1)
{
  int f = blockIdx.x * 256 + threadIdx.x;
  if (f < 2048)  { frag_store(w0, bW0, f, 13, 1);  return; }
  f -= 2048;
  if (f < 16384) { frag_store(w1, bW1, f, 512, 16); return; }
  f -= 16384;
  if (f < 2048)  { frag_store(w2, bW2, f, 256, 8);  return; }
  f -= 2048;
  if (f < 28672) { frag_store(t0, tW0, f, 415, 14); return; }
  f -= 28672;
  if (f < 16384) { frag_store(t1, tW1, f, 512, 16); return; }
}

// ---------------------------------------------------------------------------
// fused kernel. Block = 32 batch rows, 1024 threads (16 waves, 4/SIMD).
// LDS: regA 32KB: x1[32][512] -> x3[32][64] -> z1[32][512]
//      regB 28KB: dense[32][16]f32 -> x2[32][256] -> R[32][448] -> psum[16][32]
//      idxs 3.3KB: [26][32] int (preloaded in phase 0)
// ---------------------------------------------------------------------------
__global__ __launch_bounds__(1024, 1) void fused_kernel(
    const float* __restrict__ dense, const int* __restrict__ lSi,
    const float* __restrict__ Wemb,
    const _Float16* __restrict__ w0, const float* __restrict__ bb0,
    const _Float16* __restrict__ w1, const float* __restrict__ bb1,
    const _Float16* __restrict__ w2, const float* __restrict__ bb2,
    const _Float16* __restrict__ t0w, const float* __restrict__ tb0,
    const _Float16* __restrict__ t1w, const float* __restrict__ tb1,
    const float* __restrict__ tW2, const float* __restrict__ tb2,
    float* __restrict__ out)
{
  __shared__ __align__(16) char regA[32768];
  __shared__ __align__(16) char regB[28672];
  __shared__ int idxs[26 * 32];
  _Float16* x1s = (_Float16*)regA;   // [32][512]
  _Float16* x3s = (_Float16*)regA;   // [32][64]
  _Float16* z1s = (_Float16*)regA;   // [32][512]
  float*    dns = (float*)regB;      // [32][16]
  _Float16* x2s = (_Float16*)regB;   // [32][256]
  _Float16* Rs  = (_Float16*)regB;   // [32][448]
  float*    psm = (float*)regB;      // [16][32]

  const int t = threadIdx.x;
  const int lane = t & 63, wv = t >> 6;
  const int rc = lane & 15, g = lane >> 4;
  const int ko = g * 8;
  const int sw = (rc & 7) << 3;
  const int b0 = blockIdx.x * 32;

  // ---- phase 0: dense [32][13] -> LDS f32 [32][16]; lS_i -> idxs ----
  if (t < 416) {
    int r = t / 13, c = t - r * 13;
    dns[r * 16 + c] = dense[(size_t)b0 * 13 + t];
  } else if (t < 512) {
    int q = t - 416;
    int r = q / 3, c = 13 + (q - r * 3);
    dns[r * 16 + c] = 0.0f;
  } else {
    int u = t - 512;  // 512 entries
    idxs[u] = (int)lSi[(size_t)(u >> 5) * 8192 + b0 + (u & 31)];
  }
  if (t < 320) {
    int u = 512 + t;  // remaining 320 of 832
    idxs[u] = (int)lSi[(size_t)(u >> 5) * 8192 + b0 + (u & 31)];
  }
  __syncthreads();

  // ---- phase 1: L0  x1 = relu(dense @ W0^T + bb0), K=32, 32 cols/wave ----
  {
    f16x8 af[2];
#pragma unroll
    for (int rt = 0; rt < 2; ++rt) {
      f16x8 a = {};
      if (g < 2) {
        const float* s = &dns[(rt * 16 + rc) * 16 + ko];
        a = cvt8(*(const float4*)s, *(const float4*)(s + 4));
      }
      af[rt] = a;
    }
    f32x4 acc[2][2] = {};
#pragma unroll
    for (int j = 0; j < 2; ++j) {
      const int jb = wv * 2 + j;
      f16x8 wf = *(const f16x8*)&w0[(size_t)(jb * 64 + lane) * 8];
#pragma unroll
      for (int rt = 0; rt < 2; ++rt)
        acc[rt][j] = __builtin_amdgcn_mfma_f32_16x16x32_f16(af[rt], wf, acc[rt][j], 0, 0, 0);
    }
#pragma unroll
    for (int j = 0; j < 2; ++j) {
      const int col = wv * 32 + j * 16 + rc;
      const float bs = bb0[col];
#pragma unroll
      for (int rt = 0; rt < 2; ++rt)
#pragma unroll
        for (int r = 0; r < 4; ++r) {
          int row = rt * 16 + g * 4 + r;
          float v = fmaxf(acc[rt][j][r] + bs, 0.0f);
          x1s[row * 512 + (col ^ ((row & 7) << 3))] = (_Float16)v;
        }
    }
  }
  __syncthreads();

  // ---- phase 2: L1  x2 = relu(x1 @ W1^T + bb1), K=512, 16 cols/wave ----
  {
    f32x4 acc[2] = {};
#pragma unroll
    for (int kk = 0; kk < 16; ++kk) {
      f16x8 af[2];
#pragma unroll
      for (int rt = 0; rt < 2; ++rt)
        af[rt] = *(const f16x8*)&x1s[(rt * 16 + rc) * 512 + ((kk * 32 + ko) ^ sw)];
      f16x8 wf = *(const f16x8*)&w1[(size_t)((wv * 16 + kk) * 64 + lane) * 8];
#pragma unroll
      for (int rt = 0; rt < 2; ++rt)
        acc[rt] = __builtin_amdgcn_mfma_f32_16x16x32_f16(af[rt], wf, acc[rt], 0, 0, 0);
    }
    const int col = wv * 16 + rc;
    const float bs = bb1[col];
#pragma unroll
    for (int rt = 0; rt < 2; ++rt)
#pragma unroll
      for (int r = 0; r < 4; ++r) {
        int row = rt * 16 + g * 4 + r;
        float v = fmaxf(acc[rt][r] + bs, 0.0f);
        x2s[row * 256 + (col ^ ((row & 7) << 3))] = (_Float16)v;
      }
  }
  __syncthreads();

  // ---- phase 3: L2  x3 = relu(x2 @ W2^T + bb2), K=256, waves 0-7 ----
  if (wv < 8) {
    const int rt = wv & 1;
    const int cb = (wv >> 1) * 16;
    f32x4 acc = {};
#pragma unroll
    for (int kk = 0; kk < 8; ++kk) {
      f16x8 af = *(const f16x8*)&x2s[(rt * 16 + rc) * 256 + ((kk * 32 + ko) ^ sw)];
      f16x8 wf = *(const f16x8*)&w2[(size_t)(((cb >> 4) * 8 + kk) * 64 + lane) * 8];
      acc = __builtin_amdgcn_mfma_f32_16x16x32_f16(af, wf, acc, 0, 0, 0);
    }
    const int col = cb + rc;
    const float bs = bb2[col];
#pragma unroll
    for (int r = 0; r < 4; ++r) {
      int row = rt * 16 + g * 4 + r;
      float v = fmaxf(acc[r] + bs, 0.0f);
      x3s[row * 64 + col] = (_Float16)v;
    }
  }
  __syncthreads();

  // ---- phase 4: interact — 2 rows/wave; ALL 16 gather float4s in flight ----
  {
    // batch-issue: junk-address trick keeps loads branch-free
    const float* srcs[2][2];
#pragma unroll
    for (int i = 0; i < 2; ++i) {
      const int bl = wv * 2 + i;
#pragma unroll
      for (int rt = 0; rt < 2; ++rt) {
        const int gr = rt * 16 + rc;
        const bool live = (gr >= 1 && gr <= 26);
        const int tb = live ? gr - 1 : 0;
        const int idx = live ? idxs[tb * 32 + bl] : 0;
        srcs[i][rt] = Wemb + ((size_t)tb * 100000 + (size_t)idx) * 64;
      }
    }
    float4 pf[2][2][2][2];
#pragma unroll
    for (int i = 0; i < 2; ++i)
#pragma unroll
      for (int rt = 0; rt < 2; ++rt)
#pragma unroll
        for (int kh = 0; kh < 2; ++kh) {
          const float* s = srcs[i][rt] + kh * 32 + ko;
          pf[i][rt][kh][0] = *(const float4*)s;
          pf[i][rt][kh][1] = *(const float4*)(s + 4);
        }

#pragma unroll
    for (int i = 0; i < 2; ++i) {
      const int bl = wv * 2 + i;
      const int swr = (bl & 7) << 3;
      f16x8 frag[2][2];
#pragma unroll
      for (int rt = 0; rt < 2; ++rt) {
        const int gr = rt * 16 + rc;
        if (gr == 0) {
          frag[rt][0] = *(const f16x8*)&x3s[bl * 64 + ko];
          frag[rt][1] = *(const f16x8*)&x3s[bl * 64 + 32 + ko];
        } else if (gr <= 26) {
          frag[rt][0] = cvt8(pf[i][rt][0][0], pf[i][rt][0][1]);
          frag[rt][1] = cvt8(pf[i][rt][1][0], pf[i][rt][1][1]);
        } else {
          f16x8 z = {};
          frag[rt][0] = z; frag[rt][1] = z;
        }
      }
      f32x4 z00 = {}, z10 = {}, z11 = {};
#pragma unroll
      for (int kh = 0; kh < 2; ++kh) {
        z00 = __builtin_amdgcn_mfma_f32_16x16x32_f16(frag[0][kh], frag[0][kh], z00, 0, 0, 0);
        z10 = __builtin_amdgcn_mfma_f32_16x16x32_f16(frag[1][kh], frag[0][kh], z10, 0, 0, 0);
        z11 = __builtin_amdgcn_mfma_f32_16x16x32_f16(frag[1][kh], frag[1][kh], z11, 0, 0, 0);
      }
      Rs[bl * 448 + (lane ^ swr)] = x3s[bl * 64 + lane];
      if (lane < 33) Rs[bl * 448 + ((415 + lane) ^ swr)] = (_Float16)0.0f;
      const int col = lane & 15;
      const int rr0 = (lane >> 4) * 4;
#pragma unroll
      for (int r = 0; r < 4; ++r) {
        const int i0 = rr0 + r;
        if (i0 > col) {
          int p = 64 + i0 * (i0 - 1) / 2 + col;
          Rs[bl * 448 + (p ^ swr)] = (_Float16)z00[r];
        }
        const int i1 = 16 + rr0 + r;
        if (i1 < 27) {
          int p = 64 + i1 * (i1 - 1) / 2 + col;
          Rs[bl * 448 + (p ^ swr)] = (_Float16)z10[r];
          const int j1 = 16 + col;
          if (i1 > j1) {
            int q = 64 + i1 * (i1 - 1) / 2 + j1;
            Rs[bl * 448 + (q ^ swr)] = (_Float16)z11[r];
          }
        }
      }
    }
  }
  __syncthreads();

  // ---- phase 5: t0  z1 = relu(R @ T0^T + tb0), K=448, 32 cols/wave ----
  {
    f32x4 acc[2][2] = {};
#pragma unroll
    for (int kk = 0; kk < 14; ++kk) {
      f16x8 af[2];
#pragma unroll
      for (int rt = 0; rt < 2; ++rt)
        af[rt] = *(const f16x8*)&Rs[(rt * 16 + rc) * 448 + ((kk * 32 + ko) ^ sw)];
#pragma unroll
      for (int j = 0; j < 2; ++j) {
        const int jb = wv * 2 + j;
        f16x8 wf = *(const f16x8*)&t0w[(size_t)((jb * 14 + kk) * 64 + lane) * 8];
#pragma unroll
        for (int rt = 0; rt < 2; ++rt)
          acc[rt][j] = __builtin_amdgcn_mfma_f32_16x16x32_f16(af[rt], wf, acc[rt][j], 0, 0, 0);
      }
    }
#pragma unroll
    for (int j = 0; j < 2; ++j) {
      const int col = wv * 32 + j * 16 + rc;
      const float bs = tb0[col];
#pragma unroll
      for (int rt = 0; rt < 2; ++rt)
#pragma unroll
        for (int r = 0; r < 4; ++r) {
          int row = rt * 16 + g * 4 + r;
          float v = fmaxf(acc[rt][j][r] + bs, 0.0f);
          z1s[row * 512 + (col ^ ((row & 7) << 3))] = (_Float16)v;
        }
    }
  }
  __syncthreads();

  // ---- phase 6: t1 + final dot, K=512, 16 cols/wave ----
  {
    f32x4 acc[2] = {};
#pragma unroll
    for (int kk = 0; kk < 16; ++kk) {
      f16x8 af[2];
#pragma unroll
      for (int rt = 0; rt < 2; ++rt)
        af[rt] = *(const f16x8*)&z1s[(rt * 16 + rc) * 512 + ((kk * 32 + ko) ^ sw)];
      f16x8 wf = *(const f16x8*)&t1w[(size_t)((wv * 16 + kk) * 64 + lane) * 8];
#pragma unroll
      for (int rt = 0; rt < 2; ++rt)
        acc[rt] = __builtin_amdgcn_mfma_f32_16x16x32_f16(af[rt], wf, acc[rt], 0, 0, 0);
    }
    const int col = wv * 16 + rc;
    const float bz = tb1[col];
    const float wz = tW2[col];
    float pd[2][4];
#pragma unroll
    for (int rt = 0; rt < 2; ++rt)
#pragma unroll
      for (int r = 0; r < 4; ++r)
        pd[rt][r] = fmaxf(acc[rt][r] + bz, 0.0f) * wz;
    __syncthreads();  // Rs reads finished at B5; reuse regB as psum
#pragma unroll
    for (int rt = 0; rt < 2; ++rt)
#pragma unroll
      for (int r = 0; r < 4; ++r) {
        float v = pd[rt][r];
        v += __shfl_xor(v, 1, 64);
        v += __shfl_xor(v, 2, 64);
        v += __shfl_xor(v, 4, 64);
        v += __shfl_xor(v, 8, 64);
        if (rc == 0) psm[wv * 32 + rt * 16 + g * 4 + r] = v;
      }
  }
  __syncthreads();
  if (t < 32) {
    float s = tb2[0];
#pragma unroll
    for (int w = 0; w < 16; ++w) s += psm[w * 32 + t];
    out[b0 + t] = 1.0f / (1.0f + expf(-s));
  }
}

// ---------------------------------------------------------------------------
extern "C" void kernel_launch(void* const* d_in, const int* in_sizes, int n_in,
                              void* d_out, int out_size, void* d_ws, size_t ws_size,
                              hipStream_t stream)
{
  (void)in_sizes; (void)n_in; (void)out_size; (void)ws_size;
  const float* dense = (const float*)d_in[0];
  const int*   lSi   = (const int*)d_in[1];     // lS_o (d_in[2]) unused
  const float* Wemb  = (const float*)d_in[3];
  const float* bW0 = (const float*)d_in[4];  const float* bb0 = (const float*)d_in[5];
  const float* bW1 = (const float*)d_in[6];  const float* bb1 = (const float*)d_in[7];
  const float* bW2 = (const float*)d_in[8];  const float* bb2 = (const float*)d_in[9];
  const float* tW0 = (const float*)d_in[10]; const float* tb0 = (const float*)d_in[11];
  const float* tW1 = (const float*)d_in[12]; const float* tb1 = (const float*)d_in[13];
  const float* tW2 = (const float*)d_in[14]; const float* tb2 = (const float*)d_in[15];
  float* out = (float*)d_out;

  char* ws = (char*)d_ws;
  size_t off = 0;
  auto alloc = [&](size_t bytes) -> void* {
    void* p = ws + off;
    off += (bytes + 255) & ~(size_t)255;
    return p;
  };
  _Float16* w0 = (_Float16*)alloc((size_t)16384 * 2);
  _Float16* w1 = (_Float16*)alloc((size_t)131072 * 2);
  _Float16* w2 = (_Float16*)alloc((size_t)16384 * 2);
  _Float16* t0 = (_Float16*)alloc((size_t)229376 * 2);
  _Float16* t1 = (_Float16*)alloc((size_t)131072 * 2);

  prep_kernel<<<256, 256, 0, stream>>>(bW0, bW1, bW2, tW0, tW1,
                                       w0, w1, w2, t0, t1);
  fused_kernel<<<256, 1024, 0, stream>>>(dense, lSi, Wemb,
                                         w0, bb0, w1, bb1, w2, bb2,
                                         t0, tb0, t1, tb1, tW2, tb2, out);
}

// Round 14
// 36.656 us; speedup vs baseline: 1.0835x; 1.0835x over previous
//
#include <hip/hip_runtime.h>
#include <hip/hip_bf16.h>

// DLRM forward, MI355X — round 14: fused kernel = r12 verbatim (best, 36.8);
// prep vectorized (1 f16x8 fragment/thread). r13's phase-4 batch-gather and
// phase-0 idxs staging reverted (regressed: VGPR pressure + in-order vmcnt).

typedef _Float16 f16x8 __attribute__((ext_vector_type(8)));
typedef float f32x4 __attribute__((ext_vector_type(4)));

__device__ __forceinline__ f16x8 cvt8(float4 a, float4 b) {
  f16x8 f;
  f[0] = (_Float16)a.x; f[1] = (_Float16)a.y;
  f[2] = (_Float16)a.z; f[3] = (_Float16)a.w;
  f[4] = (_Float16)b.x; f[5] = (_Float16)b.y;
  f[6] = (_Float16)b.z; f[7] = (_Float16)b.w;
  return f;
}

// ---------------------------------------------------------------------------
// prep: weights -> f16 fragment-tiled images; 1 fragment (8 elems) / thread.
// elem (c,k) of [M][Kpad] -> ((j*NKK+kk)*64 + lane)*8 + e.
// Fragments: w0 2048 | w1 16384 | w2 2048 | t0 28672 | t1 16384 = 65536.
// ---------------------------------------------------------------------------
__device__ __forceinline__ void frag_store(
    _Float16* __restrict__ dst, const float* __restrict__ src,
    int fl, int Ksrc, int NKK)
{
  int lane = fl & 63, q = fl >> 6;
  int kk = q % NKK, j = q / NKK;
  int c = j * 16 + (lane & 15);
  int kb = kk * 32 + (lane >> 4) * 8;
  const float* s = src + (size_t)c * Ksrc + kb;
  f16x8 o;
#pragma unroll
  for (int e = 0; e < 8; ++e)
    o[e] = (_Float16)((kb + e < Ksrc) ? s[e] : 0.0f);
  *(f16x8*)&dst[(size_t)fl * 8] = o;
}

__global__ __launch_bounds__(256) void prep_kernel(
    const float* __restrict__ bW0, const float* __restrict__ bW1,
    const float* __restrict__ bW2, const float* __restrict__ tW0,
    const float* __restrict__ tW1,
    _Float16* __restrict__ w0, _Float16* __restrict__ w1,
    _Float16* __restrict__ w2, _Float16* __restrict__ t0,
    _Float16* __restrict__ t1)
{
  int f = blockIdx.x * 256 + threadIdx.x;
  if (f < 2048)  { frag_store(w0, bW0, f, 13, 1);  return; }
  f -= 2048;
  if (f < 16384) { frag_store(w1, bW1, f, 512, 16); return; }
  f -= 16384;
  if (f < 2048)  { frag_store(w2, bW2, f, 256, 8);  return; }
  f -= 2048;
  if (f < 28672) { frag_store(t0, tW0, f, 415, 14); return; }
  f -= 28672;
  if (f < 16384) { frag_store(t1, tW1, f, 512, 16); return; }
}

// ---------------------------------------------------------------------------
// fused kernel (r12 verbatim). Block = 32 rows, 1024 threads (16 waves).
// LDS: regA 32KB: x1[32][512] -> x3[32][64] -> z1[32][512]
//      regB 28KB: dense[32][16]f32 -> x2[32][256] -> R[32][448] -> psum[16][32]
// ---------------------------------------------------------------------------
__global__ __launch_bounds__(1024, 1) void fused_kernel(
    const float* __restrict__ dense, const int* __restrict__ lSi,
    const float* __restrict__ Wemb,
    const _Float16* __restrict__ w0, const float* __restrict__ bb0,
    const _Float16* __restrict__ w1, const float* __restrict__ bb1,
    const _Float16* __restrict__ w2, const float* __restrict__ bb2,
    const _Float16* __restrict__ t0w, const float* __restrict__ tb0,
    const _Float16* __restrict__ t1w, const float* __restrict__ tb1,
    const float* __restrict__ tW2, const float* __restrict__ tb2,
    float* __restrict__ out)
{
  __shared__ __align__(16) char regA[32768];
  __shared__ __align__(16) char regB[28672];
  _Float16* x1s = (_Float16*)regA;   // [32][512]
  _Float16* x3s = (_Float16*)regA;   // [32][64]
  _Float16* z1s = (_Float16*)regA;   // [32][512]
  float*    dns = (float*)regB;      // [32][16]
  _Float16* x2s = (_Float16*)regB;   // [32][256]
  _Float16* Rs  = (_Float16*)regB;   // [32][448]
  float*    psm = (float*)regB;      // [16][32]

  const int t = threadIdx.x;
  const int lane = t & 63, wv = t >> 6;
  const int rc = lane & 15, g = lane >> 4;
  const int ko = g * 8;
  const int sw = (rc & 7) << 3;
  const int b0 = blockIdx.x * 32;

  // ---- phase 0: dense [32][13] -> LDS f32 [32][16] ----
  if (t < 416) {
    int r = t / 13, c = t - r * 13;
    dns[r * 16 + c] = dense[(size_t)b0 * 13 + t];
  } else if (t < 512) {
    int q = t - 416;
    int r = q / 3, c = 13 + (q - r * 3);
    dns[r * 16 + c] = 0.0f;
  }
  __syncthreads();

  // ---- phase 1: L0  x1 = relu(dense @ W0^T + bb0), K=32, 32 cols/wave ----
  {
    f16x8 af[2];
#pragma unroll
    for (int rt = 0; rt < 2; ++rt) {
      f16x8 a = {};
      if (g < 2) {
        const float* s = &dns[(rt * 16 + rc) * 16 + ko];
        a = cvt8(*(const float4*)s, *(const float4*)(s + 4));
      }
      af[rt] = a;
    }
    f32x4 acc[2][2] = {};
#pragma unroll
    for (int j = 0; j < 2; ++j) {
      const int jb = wv * 2 + j;
      f16x8 wf = *(const f16x8*)&w0[(size_t)(jb * 64 + lane) * 8];
#pragma unroll
      for (int rt = 0; rt < 2; ++rt)
        acc[rt][j] = __builtin_amdgcn_mfma_f32_16x16x32_f16(af[rt], wf, acc[rt][j], 0, 0, 0);
    }
#pragma unroll
    for (int j = 0; j < 2; ++j) {
      const int col = wv * 32 + j * 16 + rc;
      const float bs = bb0[col];
#pragma unroll
      for (int rt = 0; rt < 2; ++rt)
#pragma unroll
        for (int r = 0; r < 4; ++r) {
          int row = rt * 16 + g * 4 + r;
          float v = fmaxf(acc[rt][j][r] + bs, 0.0f);
          x1s[row * 512 + (col ^ ((row & 7) << 3))] = (_Float16)v;
        }
    }
  }
  __syncthreads();

  // ---- phase 2: L1  x2 = relu(x1 @ W1^T + bb1), K=512, 16 cols/wave ----
  {
    f32x4 acc[2] = {};
#pragma unroll
    for (int kk = 0; kk < 16; ++kk) {
      f16x8 af[2];
#pragma unroll
      for (int rt = 0; rt < 2; ++rt)
        af[rt] = *(const f16x8*)&x1s[(rt * 16 + rc) * 512 + ((kk * 32 + ko) ^ sw)];
      f16x8 wf = *(const f16x8*)&w1[(size_t)((wv * 16 + kk) * 64 + lane) * 8];
#pragma unroll
      for (int rt = 0; rt < 2; ++rt)
        acc[rt] = __builtin_amdgcn_mfma_f32_16x16x32_f16(af[rt], wf, acc[rt], 0, 0, 0);
    }
    const int col = wv * 16 + rc;
    const float bs = bb1[col];
#pragma unroll
    for (int rt = 0; rt < 2; ++rt)
#pragma unroll
      for (int r = 0; r < 4; ++r) {
        int row = rt * 16 + g * 4 + r;
        float v = fmaxf(acc[rt][r] + bs, 0.0f);
        x2s[row * 256 + (col ^ ((row & 7) << 3))] = (_Float16)v;
      }
  }
  __syncthreads();

  // ---- phase 3: L2  x3 = relu(x2 @ W2^T + bb2), K=256, waves 0-7 ----
  if (wv < 8) {
    const int rt = wv & 1;
    const int cb = (wv >> 1) * 16;
    f32x4 acc = {};
#pragma unroll
    for (int kk = 0; kk < 8; ++kk) {
      f16x8 af = *(const f16x8*)&x2s[(rt * 16 + rc) * 256 + ((kk * 32 + ko) ^ sw)];
      f16x8 wf = *(const f16x8*)&w2[(size_t)(((cb >> 4) * 8 + kk) * 64 + lane) * 8];
      acc = __builtin_amdgcn_mfma_f32_16x16x32_f16(af, wf, acc, 0, 0, 0);
    }
    const int col = cb + rc;
    const float bs = bb2[col];
#pragma unroll
    for (int r = 0; r < 4; ++r) {
      int row = rt * 16 + g * 4 + r;
      float v = fmaxf(acc[r] + bs, 0.0f);
      x3s[row * 64 + col] = (_Float16)v;
    }
  }
  __syncthreads();

  // ---- phase 4: interact — 2 rows/wave: gather, Z=T*T^T, fill R slab ----
  {
    int e_idx[2][2];
#pragma unroll
    for (int i = 0; i < 2; ++i) {
      const int b = b0 + wv * 2 + i;
#pragma unroll
      for (int rt = 0; rt < 2; ++rt) {
        const int gr = rt * 16 + rc;
        e_idx[i][rt] = (gr >= 1 && gr <= 26) ? lSi[(size_t)(gr - 1) * 8192 + b] : 0;
      }
    }
#pragma unroll
    for (int i = 0; i < 2; ++i) {
      const int bl = wv * 2 + i;
      const int swr = (bl & 7) << 3;
      f16x8 frag[2][2];
#pragma unroll
      for (int rt = 0; rt < 2; ++rt) {
        const int gr = rt * 16 + rc;
        if (gr == 0) {
          frag[rt][0] = *(const f16x8*)&x3s[bl * 64 + ko];
          frag[rt][1] = *(const f16x8*)&x3s[bl * 64 + 32 + ko];
        } else if (gr <= 26) {
          const float* src = Wemb + ((size_t)(gr - 1) * 100000 + (size_t)e_idx[i][rt]) * 64;
#pragma unroll
          for (int kh = 0; kh < 2; ++kh) {
            const float* s = src + kh * 32 + ko;
            frag[rt][kh] = cvt8(*(const float4*)s, *(const float4*)(s + 4));
          }
        } else {
          f16x8 z = {};
          frag[rt][0] = z; frag[rt][1] = z;
        }
      }
      f32x4 z00 = {}, z10 = {}, z11 = {};
#pragma unroll
      for (int kh = 0; kh < 2; ++kh) {
        z00 = __builtin_amdgcn_mfma_f32_16x16x32_f16(frag[0][kh], frag[0][kh], z00, 0, 0, 0);
        z10 = __builtin_amdgcn_mfma_f32_16x16x32_f16(frag[1][kh], frag[0][kh], z10, 0, 0, 0);
        z11 = __builtin_amdgcn_mfma_f32_16x16x32_f16(frag[1][kh], frag[1][kh], z11, 0, 0, 0);
      }
      Rs[bl * 448 + (lane ^ swr)] = x3s[bl * 64 + lane];
      if (lane < 33) Rs[bl * 448 + ((415 + lane) ^ swr)] = (_Float16)0.0f;
      const int col = lane & 15;
      const int rr0 = (lane >> 4) * 4;
#pragma unroll
      for (int r = 0; r < 4; ++r) {
        const int i0 = rr0 + r;
        if (i0 > col) {
          int p = 64 + i0 * (i0 - 1) / 2 + col;
          Rs[bl * 448 + (p ^ swr)] = (_Float16)z00[r];
        }
        const int i1 = 16 + rr0 + r;
        if (i1 < 27) {
          int p = 64 + i1 * (i1 - 1) / 2 + col;
          Rs[bl * 448 + (p ^ swr)] = (_Float16)z10[r];
          const int j1 = 16 + col;
          if (i1 > j1) {
            int q = 64 + i1 * (i1 - 1) / 2 + j1;
            Rs[bl * 448 + (q ^ swr)] = (_Float16)z11[r];
          }
        }
      }
    }
  }
  __syncthreads();

  // ---- phase 5: t0  z1 = relu(R @ T0^T + tb0), K=448, 32 cols/wave ----
  {
    f32x4 acc[2][2] = {};
#pragma unroll
    for (int kk = 0; kk < 14; ++kk) {
      f16x8 af[2];
#pragma unroll
      for (int rt = 0; rt < 2; ++rt)
        af[rt] = *(const f16x8*)&Rs[(rt * 16 + rc) * 448 + ((kk * 32 + ko) ^ sw)];
#pragma unroll
      for (int j = 0; j < 2; ++j) {
        const int jb = wv * 2 + j;
        f16x8 wf = *(const f16x8*)&t0w[(size_t)((jb * 14 + kk) * 64 + lane) * 8];
#pragma unroll
        for (int rt = 0; rt < 2; ++rt)
          acc[rt][j] = __builtin_amdgcn_mfma_f32_16x16x32_f16(af[rt], wf, acc[rt][j], 0, 0, 0);
      }
    }
#pragma unroll
    for (int j = 0; j < 2; ++j) {
      const int col = wv * 32 + j * 16 + rc;
      const float bs = tb0[col];
#pragma unroll
      for (int rt = 0; rt < 2; ++rt)
#pragma unroll
        for (int r = 0; r < 4; ++r) {
          int row = rt * 16 + g * 4 + r;
          float v = fmaxf(acc[rt][j][r] + bs, 0.0f);
          z1s[row * 512 + (col ^ ((row & 7) << 3))] = (_Float16)v;
        }
    }
  }
  __syncthreads();

  // ---- phase 6: t1 + final dot, K=512, 16 cols/wave ----
  {
    f32x4 acc[2] = {};
#pragma unroll
    for (int kk = 0; kk < 16; ++kk) {
      f16x8 af[2];
#pragma unroll
      for (int rt = 0; rt < 2; ++rt)
        af[rt] = *(const f16x8*)&z1s[(rt * 16 + rc) * 512 + ((kk * 32 + ko) ^ sw)];
      f16x8 wf = *(const f16x8*)&t1w[(size_t)((wv * 16 + kk) * 64 + lane) * 8];
#pragma unroll
      for (int rt = 0; rt < 2; ++rt)
        acc[rt] = __builtin_amdgcn_mfma_f32_16x16x32_f16(af[rt], wf, acc[rt], 0, 0, 0);
    }
    const int col = wv * 16 + rc;
    const float bz = tb1[col];
    const float wz = tW2[col];
    float pd[2][4];
#pragma unroll
    for (int rt = 0; rt < 2; ++rt)
#pragma unroll
      for (int r = 0; r < 4; ++r)
        pd[rt][r] = fmaxf(acc[rt][r] + bz, 0.0f) * wz;
    __syncthreads();  // Rs reads finished at B5; reuse regB as psum
#pragma unroll
    for (int rt = 0; rt < 2; ++rt)
#pragma unroll
      for (int r = 0; r < 4; ++r) {
        float v = pd[rt][r];
        v += __shfl_xor(v, 1, 64);
        v += __shfl_xor(v, 2, 64);
        v += __shfl_xor(v, 4, 64);
        v += __shfl_xor(v, 8, 64);
        if (rc == 0) psm[wv * 32 + rt * 16 + g * 4 + r] = v;
      }
  }
  __syncthreads();
  if (t < 32) {
    float s = tb2[0];
#pragma unroll
    for (int w = 0; w < 16; ++w) s += psm[w * 32 + t];
    out[b0 + t] = 1.0f / (1.0f + expf(-s));
  }
}

// ---------------------------------------------------------------------------
extern "C" void kernel_launch(void* const* d_in, const int* in_sizes, int n_in,
                              void* d_out, int out_size, void* d_ws, size_t ws_size,
                              hipStream_t stream)
{
  (void)in_sizes; (void)n_in; (void)out_size; (void)ws_size;
  const float* dense = (const float*)d_in[0];
  const int*   lSi   = (const int*)d_in[1];     // lS_o (d_in[2]) unused
  const float* Wemb  = (const float*)d_in[3];
  const float* bW0 = (const float*)d_in[4];  const float* bb0 = (const float*)d_in[5];
  const float* bW1 = (const float*)d_in[6];  const float* bb1 = (const float*)d_in[7];
  const float* bW2 = (const float*)d_in[8];  const float* bb2 = (const float*)d_in[9];
  const float* tW0 = (const float*)d_in[10]; const float* tb0 = (const float*)d_in[11];
  const float* tW1 = (const float*)d_in[12]; const float* tb1 = (const float*)d_in[13];
  const float* tW2 = (const float*)d_in[14]; const float* tb2 = (const float*)d_in[15];
  float* out = (float*)d_out;

  char* ws = (char*)d_ws;
  size_t off = 0;
  auto alloc = [&](size_t bytes) -> void* {
    void* p = ws + off;
    off += (bytes + 255) & ~(size_t)255;
    return p;
  };
  _Float16* w0 = (_Float16*)alloc((size_t)16384 * 2);
  _Float16* w1 = (_Float16*)alloc((size_t)131072 * 2);
  _Float16* w2 = (_Float16*)alloc((size_t)16384 * 2);
  _Float16* t0 = (_Float16*)alloc((size_t)229376 * 2);
  _Float16* t1 = (_Float16*)alloc((size_t)131072 * 2);

  prep_kernel<<<256, 256, 0, stream>>>(bW0, bW1, bW2, tW0, tW1,
                                       w0, w1, w2, t0, t1);
  fused_kernel<<<256, 1024, 0, stream>>>(dense, lSi, Wemb,
                                         w0, bb0, w1, bb1, w2, bb2,
                                         t0, tb0, t1, tb1, tW2, tb2, out);
}